// Round 21
// baseline (21.216 us; speedup 1.0000x reference)
//
#include <hip/hip_runtime.h>

typedef __attribute__((ext_vector_type(8))) short bf16x8;
typedef __attribute__((ext_vector_type(4))) float f32x4;
typedef __attribute__((ext_vector_type(2))) float f32x2;
typedef __attribute__((ext_vector_type(4))) short short4v;

// Native cast -> v_cvt_pk_bf16_f32 on gfx950 (RNE).
__device__ __forceinline__ unsigned short f2bf(float x) {
    union { __bf16 h; unsigned short s; } u;
    u.h = (__bf16)x;
    return u.s;
}

// R21 = R20/R17 with ONE change: A-slice loads issue BEFORE the W staging loop
// (true T14 issue-early). In R17 the A loads issued last, so their tail latency
// was exposed at the barrier; now staging's ~32 load->cvt->ds_write iterations
// cover it. No aliasing (A -> registers; staging reads W, writes LDS) ->
// numerics bit-identical.
__global__ __launch_bounds__(256) void gemm_fused(
    const float* __restrict__ hs, const float* __restrict__ seqW,
    const float* __restrict__ hidW, const float* __restrict__ cpw,
    unsigned short* __restrict__ E16 /* [2][4096][32] bf16 */)
{
    __shared__ short wpk[32768];     // 4096 fragments x 16B = 64 KB
    __shared__ float red[4][16][32]; // 8 KB

    const int bid = blockIdx.x;
    const bool hid = bid >= 256;
    const int mt  = hid ? bid - 256 : bid;
    const int tid = threadIdx.x;
    const int wv  = tid >> 6;
    const int l   = tid & 63;
    const int l15 = l & 15;
    const int g   = l >> 4;
    const int m0  = mt * 16;
    const int mrow = m0 + l15;

    const float* __restrict__ W = hid ? hidW : seqW;
    size_t arow;
    if (hid) arow = ((size_t)(mrow >> 10) << 20) + (size_t)(mrow & 1023);
    else     arow = (size_t)mrow << 10;
    const int kbase = wv * 256;

    // ---- FIRST: issue the wave's ENTIRE A-slice (64 floats/lane) ----
    float a[64];
    if (hid) {
        const float* pa = hs + arow + (size_t)(kbase + g * 8) * 1024;
        #pragma unroll
        for (int ks = 0; ks < 8; ++ks)
            #pragma unroll
            for (int j = 0; j < 8; ++j)
                a[ks * 8 + j] = pa[(size_t)(ks * 32 + j) * 1024];
    } else {
        const f32x4* pa = (const f32x4*)(hs + arow + kbase + g * 8);
        #pragma unroll
        for (int ks = 0; ks < 8; ++ks) {
            f32x4 v0 = pa[ks * 8];
            f32x4 v1 = pa[ks * 8 + 1];
            a[ks*8+0]=v0.x; a[ks*8+1]=v0.y; a[ks*8+2]=v0.z; a[ks*8+3]=v0.w;
            a[ks*8+4]=v1.x; a[ks*8+5]=v1.y; a[ks*8+6]=v1.z; a[ks*8+7]=v1.w;
        }
    }

    // ---- THEN: stage W (32 rows x 1024 k fp32) -> LDS bf16 fragments ----
    // Its serial load->cvt->ds_write chain hides the A latency above.
    {
        const int kstep = tid >> 3;        // 0..31
        const int gg    = (tid >> 1) & 3;  // 0..3
        const int half  = tid & 1;         // k-offset 0 or 4 within fragment
        #pragma unroll 4
        for (int row = 0; row < 32; ++row) {
            f32x4 v = *(const f32x4*)(W + (size_t)row * 1024 + tid * 4);
            short4v h4 = { (short)f2bf(v.x), (short)f2bf(v.y),
                           (short)f2bf(v.z), (short)f2bf(v.w) };
            const int frag = (row >> 4) * 2048 + kstep * 64 + gg * 16 + (row & 15);
            *(short4v*)&wpk[frag * 8 + half * 4] = h4;
        }
    }

    __syncthreads();

    // ---- MFMA loop: pure register cvt + LDS B-reads, zero global accesses ----
    f32x4 acc0 = {0.f,0.f,0.f,0.f}, acc1 = {0.f,0.f,0.f,0.f};
    #pragma unroll
    for (int ks = 0; ks < 8; ++ks) {
        const int kstep = wv * 8 + ks;
        bf16x8 af, bf0, bf1;
        #pragma unroll
        for (int j = 0; j < 8; ++j) af[j] = (short)f2bf(a[ks * 8 + j]);
        bf0 = *(const bf16x8*)&wpk[(kstep * 64 + g * 16 + l15) * 8];
        bf1 = *(const bf16x8*)&wpk[(2048 + kstep * 64 + g * 16 + l15) * 8];
        acc0 = __builtin_amdgcn_mfma_f32_16x16x32_bf16(af, bf0, acc0, 0, 0, 0);
        acc1 = __builtin_amdgcn_mfma_f32_16x16x32_bf16(af, bf1, acc1, 0, 0, 0);
    }

    // C/D layout (m89-verified): col = lane&15, row = (lane>>4)*4 + reg
    #pragma unroll
    for (int r = 0; r < 4; ++r) {
        red[wv][4 * g + r][l15]      = acc0[r];
        red[wv][4 * g + r][l15 + 16] = acc1[r];
    }
    __syncthreads();

    // Sum 4 wave-partials -> fold cpw (seq only) -> bf16 pack -> 4B store.
    const int o = tid * 2;
    const float* rf = &red[0][0][0];
    float vx = rf[o]     + rf[512 + o]     + rf[1024 + o]     + rf[1536 + o];
    float vy = rf[o + 1] + rf[512 + o + 1] + rf[1024 + o + 1] + rf[1536 + o + 1];
    if (!hid) {
        f32x2 w = *(const f32x2*)(cpw + (o & 31));
        vx *= w.x; vy *= w.y;
    }
    unsigned pk = (unsigned)f2bf(vx) | ((unsigned)f2bf(vy) << 16);
    unsigned short* Eo = E16 + (hid ? (size_t)4096 * 32 : 0) + (size_t)m0 * 32 + o;
    *(unsigned*)Eo = pk;
}

// K3: rank-32 GEMM via MFMA (R14 verbatim, nt stores). Measured ~3.5us.
__global__ __launch_bounds__(256) void k3(const unsigned short* __restrict__ E16,
                                          float* __restrict__ out)
{
    const int tid = threadIdx.x;
    const int wv  = tid >> 6;
    const int l   = tid & 63;
    const int l15 = l & 15;
    const int g   = l >> 4;
    const int b   = blockIdx.z;
    const int s0  = blockIdx.y * 64 + wv * 16;
    const int h0  = blockIdx.x * 64;

    const unsigned short* As = E16 + ((size_t)(b * 1024 + s0)) * 32;
    const unsigned short* Bh = E16 + (size_t)4096 * 32 + ((size_t)(b * 1024 + h0)) * 32;

    bf16x8 af = *(const bf16x8*)(As + (size_t)l15 * 32 + g * 8);
    bf16x8 bfr[4];
    #pragma unroll
    for (int j = 0; j < 4; ++j)
        bfr[j] = *(const bf16x8*)(Bh + (size_t)(4 * l15 + j) * 32 + g * 8);

    const f32x4 zero = {0.f, 0.f, 0.f, 0.f};
    f32x4 acc[4];
    #pragma unroll
    for (int j = 0; j < 4; ++j)
        acc[j] = __builtin_amdgcn_mfma_f32_16x16x32_bf16(af, bfr[j], zero, 0, 0, 0);

    #pragma unroll
    for (int r = 0; r < 4; ++r) {
        f32x4 v = { acc[0][r], acc[1][r], acc[2][r], acc[3][r] };
        float* orow = out + ((size_t)(b * 1024 + s0 + 4 * g + r)) * 1024 + h0 + 4 * l15;
        __builtin_nontemporal_store(v, (f32x4*)orow);
    }
}

extern "C" void kernel_launch(void* const* d_in, const int* in_sizes, int n_in,
                              void* d_out, int out_size, void* d_ws, size_t ws_size,
                              hipStream_t stream) {
    const float* hs   = (const float*)d_in[0];
    // d_in[1] = all_indices: identically (n/H, n%H) -> computed implicitly
    const float* seqW = (const float*)d_in[2];
    const float* hidW = (const float*)d_in[3];
    const float* cpw  = (const float*)d_in[4];
    float* out = (float*)d_out;

    unsigned short* E16 = (unsigned short*)d_ws;   // [2][4096][32] bf16, 512 KB

    gemm_fused<<<512, 256, 0, stream>>>(hs, seqW, hidW, cpw, E16);
    dim3 grid3(16, 16, 4);
    k3<<<grid3, 256, 0, stream>>>(E16, out);
}

// Round 22
// 20.795 us; speedup vs baseline: 1.0203x; 1.0203x over previous
//
#include <hip/hip_runtime.h>

typedef __attribute__((ext_vector_type(8))) short bf16x8;
typedef __attribute__((ext_vector_type(4))) float f32x4;
typedef __attribute__((ext_vector_type(2))) float f32x2;
typedef __attribute__((ext_vector_type(4))) short short4v;

// Native cast -> v_cvt_pk_bf16_f32 on gfx950 (RNE).
__device__ __forceinline__ unsigned short f2bf(float x) {
    union { __bf16 h; unsigned short s; } u;
    u.h = (__bf16)x;
    return u.s;
}

// FINAL (R22) = R20/R17 verbatim — best measured config (20.73us, stable x2).
// Ledger: gemm ~10us (11 falsified theories), k3 ~3.5us (~write floor),
// ~2us dispatches, ~5-6us fixed graph/launch floor.
__global__ __launch_bounds__(256) void gemm_fused(
    const float* __restrict__ hs, const float* __restrict__ seqW,
    const float* __restrict__ hidW, const float* __restrict__ cpw,
    unsigned short* __restrict__ E16 /* [2][4096][32] bf16 */)
{
    __shared__ short wpk[32768];     // 4096 fragments x 16B = 64 KB
    __shared__ float red[4][16][32]; // 8 KB

    const int bid = blockIdx.x;
    const bool hid = bid >= 256;
    const int mt  = hid ? bid - 256 : bid;
    const int tid = threadIdx.x;
    const int wv  = tid >> 6;
    const int l   = tid & 63;
    const int l15 = l & 15;
    const int g   = l >> 4;
    const int m0  = mt * 16;
    const int mrow = m0 + l15;

    const float* __restrict__ W = hid ? hidW : seqW;
    size_t arow;
    if (hid) arow = ((size_t)(mrow >> 10) << 20) + (size_t)(mrow & 1023);
    else     arow = (size_t)mrow << 10;
    const int kbase = wv * 256;

    // ---- stage W (32 rows x 1024 k fp32) -> LDS bf16 fragments ----
    {
        const int kstep = tid >> 3;        // 0..31
        const int gg    = (tid >> 1) & 3;  // 0..3
        const int half  = tid & 1;         // k-offset 0 or 4 within fragment
        #pragma unroll 4
        for (int row = 0; row < 32; ++row) {
            f32x4 v = *(const f32x4*)(W + (size_t)row * 1024 + tid * 4);
            short4v h4 = { (short)f2bf(v.x), (short)f2bf(v.y),
                           (short)f2bf(v.z), (short)f2bf(v.w) };
            const int frag = (row >> 4) * 2048 + kstep * 64 + gg * 16 + (row & 15);
            *(short4v*)&wpk[frag * 8 + half * 4] = h4;
        }
    }

    // ---- issue the wave's ENTIRE A-slice into registers (64 floats/lane) ----
    float a[64];
    if (hid) {
        const float* pa = hs + arow + (size_t)(kbase + g * 8) * 1024;
        #pragma unroll
        for (int ks = 0; ks < 8; ++ks)
            #pragma unroll
            for (int j = 0; j < 8; ++j)
                a[ks * 8 + j] = pa[(size_t)(ks * 32 + j) * 1024];
    } else {
        const f32x4* pa = (const f32x4*)(hs + arow + kbase + g * 8);
        #pragma unroll
        for (int ks = 0; ks < 8; ++ks) {
            f32x4 v0 = pa[ks * 8];
            f32x4 v1 = pa[ks * 8 + 1];
            a[ks*8+0]=v0.x; a[ks*8+1]=v0.y; a[ks*8+2]=v0.z; a[ks*8+3]=v0.w;
            a[ks*8+4]=v1.x; a[ks*8+5]=v1.y; a[ks*8+6]=v1.z; a[ks*8+7]=v1.w;
        }
    }

    __syncthreads();

    // ---- MFMA loop: pure register cvt + LDS B-reads, zero global accesses ----
    f32x4 acc0 = {0.f,0.f,0.f,0.f}, acc1 = {0.f,0.f,0.f,0.f};
    #pragma unroll
    for (int ks = 0; ks < 8; ++ks) {
        const int kstep = wv * 8 + ks;
        bf16x8 af, bf0, bf1;
        #pragma unroll
        for (int j = 0; j < 8; ++j) af[j] = (short)f2bf(a[ks * 8 + j]);
        bf0 = *(const bf16x8*)&wpk[(kstep * 64 + g * 16 + l15) * 8];
        bf1 = *(const bf16x8*)&wpk[(2048 + kstep * 64 + g * 16 + l15) * 8];
        acc0 = __builtin_amdgcn_mfma_f32_16x16x32_bf16(af, bf0, acc0, 0, 0, 0);
        acc1 = __builtin_amdgcn_mfma_f32_16x16x32_bf16(af, bf1, acc1, 0, 0, 0);
    }

    // C/D layout (m89-verified): col = lane&15, row = (lane>>4)*4 + reg
    #pragma unroll
    for (int r = 0; r < 4; ++r) {
        red[wv][4 * g + r][l15]      = acc0[r];
        red[wv][4 * g + r][l15 + 16] = acc1[r];
    }
    __syncthreads();

    // Sum 4 wave-partials -> fold cpw (seq only) -> bf16 pack -> 4B store.
    const int o = tid * 2;
    const float* rf = &red[0][0][0];
    float vx = rf[o]     + rf[512 + o]     + rf[1024 + o]     + rf[1536 + o];
    float vy = rf[o + 1] + rf[512 + o + 1] + rf[1024 + o + 1] + rf[1536 + o + 1];
    if (!hid) {
        f32x2 w = *(const f32x2*)(cpw + (o & 31));
        vx *= w.x; vy *= w.y;
    }
    unsigned pk = (unsigned)f2bf(vx) | ((unsigned)f2bf(vy) << 16);
    unsigned short* Eo = E16 + (hid ? (size_t)4096 * 32 : 0) + (size_t)m0 * 32 + o;
    *(unsigned*)Eo = pk;
}

// K3: rank-32 GEMM via MFMA (R14 verbatim, nt stores). Measured ~3.5us.
__global__ __launch_bounds__(256) void k3(const unsigned short* __restrict__ E16,
                                          float* __restrict__ out)
{
    const int tid = threadIdx.x;
    const int wv  = tid >> 6;
    const int l   = tid & 63;
    const int l15 = l & 15;
    const int g   = l >> 4;
    const int b   = blockIdx.z;
    const int s0  = blockIdx.y * 64 + wv * 16;
    const int h0  = blockIdx.x * 64;

    const unsigned short* As = E16 + ((size_t)(b * 1024 + s0)) * 32;
    const unsigned short* Bh = E16 + (size_t)4096 * 32 + ((size_t)(b * 1024 + h0)) * 32;

    bf16x8 af = *(const bf16x8*)(As + (size_t)l15 * 32 + g * 8);
    bf16x8 bfr[4];
    #pragma unroll
    for (int j = 0; j < 4; ++j)
        bfr[j] = *(const bf16x8*)(Bh + (size_t)(4 * l15 + j) * 32 + g * 8);

    const f32x4 zero = {0.f, 0.f, 0.f, 0.f};
    f32x4 acc[4];
    #pragma unroll
    for (int j = 0; j < 4; ++j)
        acc[j] = __builtin_amdgcn_mfma_f32_16x16x32_bf16(af, bfr[j], zero, 0, 0, 0);

    #pragma unroll
    for (int r = 0; r < 4; ++r) {
        f32x4 v = { acc[0][r], acc[1][r], acc[2][r], acc[3][r] };
        float* orow = out + ((size_t)(b * 1024 + s0 + 4 * g + r)) * 1024 + h0 + 4 * l15;
        __builtin_nontemporal_store(v, (f32x4*)orow);
    }
}

extern "C" void kernel_launch(void* const* d_in, const int* in_sizes, int n_in,
                              void* d_out, int out_size, void* d_ws, size_t ws_size,
                              hipStream_t stream) {
    const float* hs   = (const float*)d_in[0];
    // d_in[1] = all_indices: identically (n/H, n%H) -> computed implicitly
    const float* seqW = (const float*)d_in[2];
    const float* hidW = (const float*)d_in[3];
    const float* cpw  = (const float*)d_in[4];
    float* out = (float*)d_out;

    unsigned short* E16 = (unsigned short*)d_ws;   // [2][4096][32] bf16, 512 KB

    gemm_fused<<<512, 256, 0, stream>>>(hs, seqW, hidW, cpw, E16);
    dim3 grid3(16, 16, 4);
    k3<<<grid3, 256, 0, stream>>>(E16, out);
}